// Round 5
// baseline (11414.733 us; speedup 1.0000x reference)
//
#include <hip/hip_runtime.h>

// Problem constants (from reference)
#define SEQ   8192
#define HID   256
#define G3    768      // 3*HID
#define TSTART 1024    // SEQ/8
#define NEGD  1365     // SEQ/6
#define TCNT  5791     // (SEQ - 10 - NEGD - 4 + 2) - TSTART
#define DENOMF 23164.0f // TCNT*4

typedef _Float16 half2_t __attribute__((ext_vector_type(2)));

__device__ __forceinline__ float fdot2(half2_t a, half2_t b, float c) {
#if __has_builtin(__builtin_amdgcn_fdot2)
  return __builtin_amdgcn_fdot2(a, b, c, false);
#else
  return c + (float)a.x * (float)b.x + (float)a.y * (float)b.y;
#endif
}

__device__ __forceinline__ half2_t h2_from_u32(unsigned int u) {
  return __builtin_bit_cast(half2_t, u);
}

__device__ __forceinline__ float sigmoidf_fast(float x) {
  return 1.0f / (1.0f + __expf(-x));
}
// tanh via sigmoid form: safe at both extremes (exp under/overflow -> +-1)
__device__ __forceinline__ float tanhf_fast(float x) {
  return 2.0f / (1.0f + __expf(-2.0f * x)) - 1.0f;
}

// Sum across the 4 lanes of each aligned quad (lane^1 then lane^2), on the
// VALU via quad_perm DPP -- the standard rocPRIM wave-reduce pattern.
// 0xB1 = [1,0,3,2], 0x4E = [2,3,0,1]. All lanes active (full block runs the
// loop), so old-value semantics of disabled lanes never matter.
__device__ __forceinline__ float quad_sum(float x) {
#if __has_builtin(__builtin_amdgcn_update_dpp)
  int xi = __builtin_bit_cast(int, x);
  int a  = __builtin_amdgcn_update_dpp(xi, xi, 0xB1, 0xF, 0xF, false);
  float y = x + __builtin_bit_cast(float, a);
  int yi = __builtin_bit_cast(int, y);
  int b  = __builtin_amdgcn_update_dpp(yi, yi, 0x4E, 0xF, 0xF, false);
  return y + __builtin_bit_cast(float, b);
#else
  float y = x + __shfl_xor(x, 1, 64);
  return y + __shfl_xor(y, 2, 64);
#endif
}

// ---------------------------------------------------------------------------
// init: zero the loss accumulators (ws is poisoned 0xAA every call)
// ---------------------------------------------------------------------------
__global__ void init_kernel(float* accum) {
  if (threadIdx.x < 2) accum[threadIdx.x] = 0.0f;
}

// ---------------------------------------------------------------------------
// Phase A: xW = data @ Wih^T + bih -> f32 [SEQ][768]. All f32.
// grid (256, 3), block 256. Thread owns output col o; 32-row x-tile in LDS.
// ---------------------------------------------------------------------------
__global__ __launch_bounds__(256) void xw_kernel(
    const float* __restrict__ data, const float* __restrict__ Wih,
    const float* __restrict__ bih, float* __restrict__ xw)
{
  __shared__ float4 xs4[32 * 64];   // 32 rows x 256 f32 = 32 KB
  const int o  = blockIdx.y * 256 + threadIdx.x;
  const int m0 = blockIdx.x * 32;

  float* xsf = (float*)xs4;
  for (int r = 0; r < 32; ++r)
    xsf[r * 256 + threadIdx.x] = data[(size_t)(m0 + r) * 256 + threadIdx.x];
  __syncthreads();

  const float b = bih[o];
  float acc[32];
#pragma unroll
  for (int r = 0; r < 32; ++r) acc[r] = b;

  const float4* wrow = (const float4*)(Wih + (size_t)o * 256);
  for (int kc = 0; kc < 4; ++kc) {
    float4 w[16];
#pragma unroll
    for (int j = 0; j < 16; ++j) w[j] = wrow[kc * 16 + j];
#pragma unroll
    for (int r = 0; r < 32; ++r) {
      const float4* xr = xs4 + r * 64 + kc * 16;
      float a0 = 0.f, a1 = 0.f, a2 = 0.f, a3 = 0.f;
#pragma unroll
      for (int j = 0; j < 4; ++j) {
        float4 x0 = xr[4 * j + 0], x1 = xr[4 * j + 1];
        float4 x2 = xr[4 * j + 2], x3 = xr[4 * j + 3];
        float4 w0 = w[4 * j + 0], w1 = w[4 * j + 1];
        float4 w2 = w[4 * j + 2], w3 = w[4 * j + 3];
        a0 = fmaf(w0.x, x0.x, fmaf(w0.y, x0.y, fmaf(w0.z, x0.z, fmaf(w0.w, x0.w, a0))));
        a1 = fmaf(w1.x, x1.x, fmaf(w1.y, x1.y, fmaf(w1.z, x1.z, fmaf(w1.w, x1.w, a1))));
        a2 = fmaf(w2.x, x2.x, fmaf(w2.y, x2.y, fmaf(w2.z, x2.z, fmaf(w2.w, x2.w, a2))));
        a3 = fmaf(w3.x, x3.x, fmaf(w3.y, x3.y, fmaf(w3.z, x3.z, fmaf(w3.w, x3.w, a3))));
      }
      acc[r] += (a0 + a1) + (a2 + a3);
    }
  }
  for (int r = 0; r < 32; ++r)
    xw[(size_t)(m0 + r) * G3 + o] = acc[r];
}

// ---------------------------------------------------------------------------
// data row norms: one wave per row (f32 data)
// ---------------------------------------------------------------------------
__global__ __launch_bounds__(256) void rnorm_kernel(
    const float* __restrict__ data, float* __restrict__ rn)
{
  int wave = threadIdx.x >> 6, lane = threadIdx.x & 63;
  int row = blockIdx.x * 4 + wave;
  const float* xr = data + (size_t)row * HID;
  float a = xr[lane], b = xr[lane + 64], c = xr[lane + 128], d = xr[lane + 192];
  float s = a * a + b * b + c * c + d * d;
#pragma unroll
  for (int off = 32; off; off >>= 1) s += __shfl_xor(s, off, 64);
  if (lane == 0) rn[row] = fmaxf(sqrtf(s), 1e-8f);
}

// ---------------------------------------------------------------------------
// Phase B: sequential GRU scan, VALU fdot2. ONE block, 512 threads (8 waves,
// 2/SIMD).
//
// Cost model that drove this shape (all per step): VALU floor = 196K MACs /
// (2 MACs * 64 lanes * 4 SIMDs * 2waves issue) = 768 cyc/SIMD; the previous
// MFMA matvec's floor was ~1860 cyc/SIMD (15/16 of each MFMA wasted on
// replicated B-columns). LDS broadcast traffic = threads * bytes-each-reads,
// so thread granularity is 6 rows (2 cols x 3 gates) over a k-QUARTER:
// 512 threads x 128 B = 65 KB/step (~350-580 cyc/CU), half of the round-3
// layout. Weight budget unchanged: 6 rows x 32 half2 = 192 regs.
//
// kq = lane&3 picks the k-quarter; cross-k reduce = 2-stage quad_perm DPP
// add (VALU pipe, no LDS, no barrier). h is stored with a 144-B quarter
// stride so the 4 kq read-addresses land on disjoint bank groups (a 128-B
// stride would alias all quarters onto the same 4 banks = 4-way conflict);
// within a quarter all 16 lanes read the same 16 B = pure multicast.
// ONE barrier per step (writers write hbuf[(s+1)&1], read next step).
// ---------------------------------------------------------------------------
#define QSTRIDE 72   // halves per h-quarter slot (64 data + 8 pad = 144 B)

__global__ __launch_bounds__(512, 2) void gru_kernel(
    const float* __restrict__ Whh, const float* __restrict__ bhh,
    const float* __restrict__ xw, float* __restrict__ zout)
{
  __shared__ _Float16 hbuf[2][4 * QSTRIDE];  // 2 x 576 B, bank-spread quarters
  const int i    = threadIdx.x;
  const int wave = i >> 6;
  const int lane = i & 63;
  const int kq   = lane & 3;                 // k-quarter [64*kq, 64*kq+64)
  const int p    = wave * 16 + (lane >> 2);  // column pair index 0..127
  const int c0   = 2 * p, c1 = c0 + 1;
  const int qc   = c0 >> 6;                  // h-quarter my columns live in
  const int wc   = c0 & 63;

  // --- resident weights: rows {r,z,n} x {c0,c1}, k in [64kq, 64kq+64) ---
  // W[t][j]: t = G*2 + cc, j = k-pair index (global k = 64*kq + 2j).
  half2_t W[6][32];
#pragma unroll
  for (int G = 0; G < 3; ++G)
#pragma unroll
    for (int cc = 0; cc < 2; ++cc) {
      const int row = G * 256 + c0 + cc;
      const float4* wp = (const float4*)(Whh + (size_t)row * 256 + kq * 64);
#pragma unroll
      for (int m = 0; m < 16; ++m) {
        float4 a = wp[m];
        half2_t p0; p0.x = (_Float16)a.x; p0.y = (_Float16)a.y;
        half2_t p1; p1.x = (_Float16)a.z; p1.y = (_Float16)a.w;
        W[G * 2 + cc][2 * m]     = p0;
        W[G * 2 + cc][2 * m + 1] = p1;
      }
    }

  const float br0 = bhh[c0],       br1 = bhh[c1];
  const float bz0 = bhh[256 + c0], bz1 = bhh[256 + c1];
  const float bn0 = bhh[512 + c0], bn1 = bhh[512 + c1];

  if (i < 4 * QSTRIDE) hbuf[0][i] = (_Float16)0.0f;
  __syncthreads();

  float h0 = 0.0f, h1 = 0.0f;   // h[c0], h[c1] (tracked by all 4 kq copies)
  // xw prefetch regs (float2: c0,c1 adjacent)
  float2 xr = *(const float2*)(xw + c0);
  float2 xz = *(const float2*)(xw + 256 + c0);
  float2 xn = *(const float2*)(xw + 512 + c0);

  for (int s = 0; s < SEQ; ++s) {
    // issue next step's xW loads now (L2 latency hidden behind the dots)
    const size_t bnext = (size_t)(s + 1 < SEQ ? s + 1 : s) * G3;
    float2 xr1 = *(const float2*)(xw + bnext + c0);
    float2 xz1 = *(const float2*)(xw + bnext + 256 + c0);
    float2 xn1 = *(const float2*)(xw + bnext + 512 + c0);

    // --- 6 quarter-dots against this thread's h-quarter (LDS multicast) ---
    const uint4* hq = (const uint4*)(hbuf[s & 1] + kq * QSTRIDE);
    uint4 q[4];
#pragma unroll
    for (int m = 0; m < 4; ++m) q[m] = hq[m];

    float a0 = 0.f, a1 = 0.f, a2 = 0.f, a3 = 0.f, a4 = 0.f, a5 = 0.f;
#pragma unroll
    for (int m = 0; m < 8; ++m) {
      uint4 cur = q[m & 3];
      if (m + 4 < 8) q[m & 3] = hq[m + 4];
      half2_t hx = h2_from_u32(cur.x), hy = h2_from_u32(cur.y);
      half2_t hz = h2_from_u32(cur.z), hw = h2_from_u32(cur.w);
      a0 = fdot2(W[0][4 * m + 0], hx, a0);
      a1 = fdot2(W[1][4 * m + 0], hx, a1);
      a2 = fdot2(W[2][4 * m + 0], hx, a2);
      a3 = fdot2(W[3][4 * m + 0], hx, a3);
      a4 = fdot2(W[4][4 * m + 0], hx, a4);
      a5 = fdot2(W[5][4 * m + 0], hx, a5);
      a0 = fdot2(W[0][4 * m + 1], hy, a0);
      a1 = fdot2(W[1][4 * m + 1], hy, a1);
      a2 = fdot2(W[2][4 * m + 1], hy, a2);
      a3 = fdot2(W[3][4 * m + 1], hy, a3);
      a4 = fdot2(W[4][4 * m + 1], hy, a4);
      a5 = fdot2(W[5][4 * m + 1], hy, a5);
      a0 = fdot2(W[0][4 * m + 2], hz, a0);
      a1 = fdot2(W[1][4 * m + 2], hz, a1);
      a2 = fdot2(W[2][4 * m + 2], hz, a2);
      a3 = fdot2(W[3][4 * m + 2], hz, a3);
      a4 = fdot2(W[4][4 * m + 2], hz, a4);
      a5 = fdot2(W[5][4 * m + 2], hz, a5);
      a0 = fdot2(W[0][4 * m + 3], hw, a0);
      a1 = fdot2(W[1][4 * m + 3], hw, a1);
      a2 = fdot2(W[2][4 * m + 3], hw, a2);
      a3 = fdot2(W[3][4 * m + 3], hw, a3);
      a4 = fdot2(W[4][4 * m + 3], hw, a4);
      a5 = fdot2(W[5][4 * m + 3], hw, a5);
    }

    // --- cross-quarter reduce within each lane-quad (VALU DPP, no barrier) ---
    float yr0 = quad_sum(a0), yr1 = quad_sum(a1);
    float yz0 = quad_sum(a2), yz1 = quad_sum(a3);
    float yn0 = quad_sum(a4), yn1 = quad_sum(a5);

    // --- gate math for both owned columns (redundant in all 4 kq copies) ---
    float rg0 = sigmoidf_fast(yr0 + br0 + xr.x);
    float rg1 = sigmoidf_fast(yr1 + br1 + xr.y);
    float zg0 = sigmoidf_fast(yz0 + bz0 + xz.x);
    float zg1 = sigmoidf_fast(yz1 + bz1 + xz.y);
    float ng0 = tanhf_fast(xn.x + rg0 * (yn0 + bn0));
    float ng1 = tanhf_fast(xn.y + rg1 * (yn1 + bn1));
    h0 = (1.0f - zg0) * ng0 + zg0 * h0;
    h1 = (1.0f - zg1) * ng1 + zg1 * h1;

    if (kq == 0) {   // one copy per pair publishes h (packed f16x2) + z
      half2_t hp; hp.x = (_Float16)h0; hp.y = (_Float16)h1;
      *(unsigned int*)(&hbuf[(s + 1) & 1][qc * QSTRIDE + wc]) =
          __builtin_bit_cast(unsigned int, hp);
      float2 zv; zv.x = h0; zv.y = h1;
      *(float2*)(zout + (size_t)s * HID + c0) = zv;
    }
    __syncthreads();
    xr = xr1; xz = xz1; xn = xn1;
  }
}

// ---------------------------------------------------------------------------
// Phase C: NCE loss + accuracy. One block per t, 4 waves = 4 timespans.
// Reads f32 z straight from d_out.
// ---------------------------------------------------------------------------
__global__ __launch_bounds__(256) void cpc_kernel(
    const float* __restrict__ x, const float* __restrict__ zf,
    const float* __restrict__ rn, float* __restrict__ accum)
{
  __shared__ float zsh[HID];
  __shared__ float wsum[4];
  __shared__ float nce_s[4], acc_s[4];
  const int tt = TSTART + blockIdx.x;
  const int i = threadIdx.x;
  const int wave = i >> 6, lane = i & 63;

  float zi = zf[(size_t)tt * HID + i];
  zsh[i] = zi;
  float p = zi * zi;
#pragma unroll
  for (int off = 32; off; off >>= 1) p += __shfl_xor(p, off, 64);
  if (lane == 0) wsum[wave] = p;
  __syncthreads();
  float zn = fmaxf(sqrtf(wsum[0] + wsum[1] + wsum[2] + wsum[3]), 1e-8f);

  float z0 = zsh[lane], z1 = zsh[lane + 64], z2 = zsh[lane + 128], z3 = zsh[lane + 192];
  const int base = tt + wave + 1;   // pos index for timespan (wave+1)

  float tot[10];
#pragma unroll
  for (int n = 0; n < 10; ++n) {
    int idx = base + (n > 0 ? (NEGD + n - 1) : 0);
    const float* xr = x + (size_t)idx * HID;
    float q = xr[lane] * z0 + xr[lane + 64] * z1 + xr[lane + 128] * z2 + xr[lane + 192] * z3;
#pragma unroll
    for (int off = 32; off; off >>= 1) q += __shfl_xor(q, off, 64);
    tot[n] = q / (rn[idx] * zn);
  }
  float m = tot[0];
#pragma unroll
  for (int n = 1; n < 10; ++n) m = fmaxf(m, tot[n]);
  float se = 0.f;
#pragma unroll
  for (int n = 0; n < 10; ++n) se += expf(tot[n] - m);
  float logp0 = (tot[0] - m) - logf(se);
  float accv = (tot[0] >= m) ? 1.0f : 0.0f;  // argmax==0 iff tot[0] is the max

  if (lane == 0) { nce_s[wave] = -logp0; acc_s[wave] = accv; }
  __syncthreads();
  if (i == 0) {
    atomicAdd(accum,     nce_s[0] + nce_s[1] + nce_s[2] + nce_s[3]);
    atomicAdd(accum + 1, acc_s[0] + acc_s[1] + acc_s[2] + acc_s[3]);
  }
}

__global__ void fin_kernel(const float* __restrict__ accum,
                           float* __restrict__ out)
{
  if (threadIdx.x == 0) {
    out[(size_t)SEQ * HID]     = accum[0] / DENOMF;   // nce
    out[(size_t)SEQ * HID + 1] = accum[1] / DENOMF;   // acc
  }
}

// ---------------------------------------------------------------------------
extern "C" void kernel_launch(void* const* d_in, const int* in_sizes, int n_in,
                              void* d_out, int out_size, void* d_ws, size_t ws_size,
                              hipStream_t stream)
{
  // Inputs are f32 (reference dtypes). Output f32: z [SEQ*HID] | nce | acc.
  const float* data = (const float*)d_in[0];
  const float* Wih  = (const float*)d_in[1];
  const float* Whh  = (const float*)d_in[2];
  const float* bih  = (const float*)d_in[3];
  const float* bhh  = (const float*)d_in[4];
  float* out = (float*)d_out;

  // ws layout: xw f32 [SEQ*768] 25.17MB | rn f32 [SEQ] | accum f32 [2]
  char* p = (char*)d_ws;
  float* xw    = (float*)p;  p += (size_t)SEQ * G3 * sizeof(float);
  float* rn    = (float*)p;  p += (size_t)SEQ * sizeof(float);
  float* accum = (float*)p;

  init_kernel<<<1, 64, 0, stream>>>(accum);
  xw_kernel<<<dim3(256, 3), 256, 0, stream>>>(data, Wih, bih, xw);
  rnorm_kernel<<<SEQ / 4, 256, 0, stream>>>(data, rn);
  gru_kernel<<<1, 512, 0, stream>>>(Whh, bhh, xw, out);
  cpc_kernel<<<TCNT, 256, 0, stream>>>(data, out, rn, accum);
  fin_kernel<<<1, 1, 0, stream>>>(accum, out);
}